// Round 5
// baseline (1273.119 us; speedup 1.0000x reference)
//
#include <hip/hip_runtime.h>
#include <math.h>

// Problem constants
constexpr int B_   = 32;
constexpr int G_   = 8;
constexpr int CIN  = 64;
constexpr int CAPS = 4;
constexpr int OUTC = 64;
constexpr int HID  = 512;           // CIN * RATIO
constexpr int CO   = CAPS * OUTC;   // 256
constexpr int HW   = 64 * 64;       // 4096

// workspace layout (floats)
constexpr int WS_POOLED = 0;              // B*G*CIN = 16384
constexpr int WS_ATTS   = 16384;          // B*G*CO  = 65536
constexpr int WS_MATT   = 16384 + 65536;  // B*CO    = 8192
constexpr int WS_CNT    = 16384 + 65536 + 8192;  // 256 + 32 ints

// ---------------------------------------------------------------------------
// K1: pool one channel per block; last block of each (b,g) runs the MLP;
//     last (b,g) of each batch runs the dynamic routing. No grid barrier.
// ---------------------------------------------------------------------------
__global__ __launch_bounds__(256, 4) void pool_mlp_routing(
    const float* __restrict__ emb,
    const float* __restrict__ w1, const float* __restrict__ b1,
    const float* __restrict__ w2, const float* __restrict__ b2,
    float* __restrict__ pooled, float* __restrict__ atts,
    float* __restrict__ matt, int* __restrict__ cnt)
{
    const int bid = blockIdx.x, tid = threadIdx.x;
    const int bg = bid >> 6;              // b*G + g  in [0,256)
    const int b  = bg >> 3, g = bg & 7;
    int* cnt_bg = cnt;                    // 256 counters
    int* cnt_b  = cnt + 256;              // 32 counters

    // ---- pool: mean over HW of channel `bid` ----
    {
        const float4* p = reinterpret_cast<const float4*>(emb + (size_t)bid * HW);
        float s = 0.f;
        #pragma unroll
        for (int k = 0; k < 4; ++k) {
            float4 v = p[tid + k * 256];
            s += v.x + v.y + v.z + v.w;
        }
        #pragma unroll
        for (int off = 32; off; off >>= 1) s += __shfl_down(s, off);
        __shared__ float wsum[4];
        if ((tid & 63) == 0) wsum[tid >> 6] = s;
        __syncthreads();
        if (tid == 0)
            pooled[bid] = (wsum[0] + wsum[1] + wsum[2] + wsum[3]) * (1.0f / HW);
    }

    // ---- last-of-64 election for this (b,g) ----
    __shared__ int lastflag;
    if (tid == 0) {
        __threadfence();
        lastflag = (atomicAdd(&cnt_bg[bg], 1) == 63);
    }
    __syncthreads();
    if (!lastflag) return;
    __threadfence();   // acquire: see all 64 pooled writes

    // ---- MLP for (b,g): h = relu(pin @ W1^T + b1); atts = h @ W2^T + b2 ----
    __shared__ float pin[CIN];
    __shared__ float h[HID];
    if (tid < CIN) pin[tid] = pooled[(size_t)bg * CIN + tid];
    __syncthreads();

    const float* W1 = w1 + (size_t)g * HID * CIN;
    #pragma unroll
    for (int oo = 0; oo < 2; ++oo) {
        const int o = tid + oo * 256;
        const float4* wrow = reinterpret_cast<const float4*>(W1 + (size_t)o * CIN);
        float acc = b1[g * HID + o];
        #pragma unroll
        for (int i = 0; i < CIN / 4; ++i) {
            float4 w = wrow[i];
            acc += w.x * pin[4 * i] + w.y * pin[4 * i + 1] +
                   w.z * pin[4 * i + 2] + w.w * pin[4 * i + 3];
        }
        h[o] = fmaxf(acc, 0.f);
    }
    __syncthreads();

    {
        const float* W2 = w2 + (size_t)g * CO * HID;
        const float4* wrow = reinterpret_cast<const float4*>(W2 + (size_t)tid * HID);
        float acc = b2[g * CO + tid];
        #pragma unroll 8
        for (int i = 0; i < HID / 4; ++i) {
            float4 w = wrow[i];
            acc += w.x * h[4 * i] + w.y * h[4 * i + 1] +
                   w.z * h[4 * i + 2] + w.w * h[4 * i + 3];
        }
        atts[(size_t)bg * CO + tid] = acc;
    }
    __syncthreads();

    // ---- last-of-8 election for this batch ----
    if (tid == 0) {
        __threadfence();
        lastflag = (atomicAdd(&cnt_b[b], 1) == 7);
    }
    __syncthreads();
    if (!lastflag) return;
    __threadfence();   // acquire: see all 8 groups' atts

    // ---- dynamic routing for batch b ----
    __shared__ float xr[G_ * CAPS * OUTC];   // 2048
    __shared__ float beta[G_ * CAPS];
    __shared__ float alpha[G_ * CAPS];
    __shared__ float vv[CAPS * OUTC];        // 256
    __shared__ float nrm[CAPS];
    for (int i = tid; i < G_ * CAPS * OUTC; i += 256)
        xr[i] = atts[(size_t)b * G_ * CO + i];
    if (tid < G_ * CAPS) beta[tid] = 0.f;
    __syncthreads();

    for (int iter = 0; iter < 3; ++iter) {
        if (tid < G_ * CAPS) {
            const int gg = tid / CAPS;
            float m = fmaxf(fmaxf(beta[gg * CAPS + 0], beta[gg * CAPS + 1]),
                            fmaxf(beta[gg * CAPS + 2], beta[gg * CAPS + 3]));
            float se = 0.f;
            #pragma unroll
            for (int c = 0; c < CAPS; ++c) se += expf(beta[gg * CAPS + c] - m);
            alpha[tid] = expf(beta[tid] - m) / se;
        }
        __syncthreads();
        {
            const int c = tid >> 6;
            float acc = 0.f;
            #pragma unroll
            for (int gg = 0; gg < G_; ++gg)
                acc += alpha[gg * CAPS + c] * xr[(gg * CAPS + c) * OUTC + (tid & 63)];
            vv[tid] = acc;
        }
        __syncthreads();
        if (iter == 2) {
            matt[(size_t)b * CO + tid] = 1.f / (1.f + expf(-vv[tid]));
        } else {
            float sq = vv[tid] * vv[tid];
            #pragma unroll
            for (int off = 32; off; off >>= 1) sq += __shfl_down(sq, off);
            if ((tid & 63) == 0) nrm[tid >> 6] = sqrtf(sq);
            __syncthreads();
            if (tid < G_ * CAPS) {
                const int gg = tid / CAPS, c = tid % CAPS;
                const float inv = 1.f / fmaxf(nrm[c], 1e-12f);
                float acc = 0.f;
                #pragma unroll
                for (int o = 0; o < OUTC; ++o)
                    acc += vv[c * OUTC + o] * xr[(gg * CAPS + c) * OUTC + o];
                beta[tid] += acc * inv;
            }
            __syncthreads();
        }
    }
}

// ---------------------------------------------------------------------------
// K2: out[b,c,:,:] = matt[b,c] * x[b,c,:,:]   (float4 grid-stride)
// ---------------------------------------------------------------------------
__global__ __launch_bounds__(256) void scale_kernel(const float* __restrict__ x,
                                                    const float* __restrict__ matt,
                                                    float* __restrict__ out,
                                                    int total4) {
    const int stride = gridDim.x * blockDim.x;
    const float4* xi = reinterpret_cast<const float4*>(x);
    float4* oi = reinterpret_cast<float4*>(out);
    for (int i = blockIdx.x * blockDim.x + threadIdx.x; i < total4; i += stride) {
        const int ch = i >> 10;          // 1024 float4 per channel
        const float s = matt[ch];
        float4 v = xi[i];
        v.x *= s; v.y *= s; v.z *= s; v.w *= s;
        oi[i] = v;
    }
}

extern "C" void kernel_launch(void* const* d_in, const int* in_sizes, int n_in,
                              void* d_out, int out_size, void* d_ws, size_t ws_size,
                              hipStream_t stream) {
    const float* emb = (const float*)d_in[0];
    const float* x   = (const float*)d_in[1];
    const float* w1  = (const float*)d_in[2];
    const float* b1  = (const float*)d_in[3];
    const float* w2  = (const float*)d_in[4];
    const float* b2  = (const float*)d_in[5];
    float* out = (float*)d_out;

    float* wsf    = (float*)d_ws;
    float* pooled = wsf + WS_POOLED;
    float* atts   = wsf + WS_ATTS;
    float* matt   = wsf + WS_MATT;
    int*   cnt    = (int*)(wsf + WS_CNT);

    hipMemsetAsync(cnt, 0, (256 + 32) * sizeof(int), stream);
    pool_mlp_routing<<<B_ * G_ * CIN, 256, 0, stream>>>(emb, w1, b1, w2, b2,
                                                        pooled, atts, matt, cnt);
    const int total4 = B_ * CO * (HW / 4);    // 8,388,608
    scale_kernel<<<2048, 256, 0, stream>>>(x, matt, out, total4);
}

// Round 6
// 139.601 us; speedup vs baseline: 9.1197x; 9.1197x over previous
//
#include <hip/hip_runtime.h>
#include <math.h>

// Problem constants
constexpr int B_   = 32;
constexpr int G_   = 8;
constexpr int CIN  = 64;
constexpr int CAPS = 4;
constexpr int OUTC = 64;
constexpr int HID  = 512;           // CIN * RATIO
constexpr int CO   = CAPS * OUTC;   // 256
constexpr int HW   = 64 * 64;       // 4096

// ---------------------------------------------------------------------------
// K1: one block per (b,g). Pool 64 channels -> LDS, fc1 -> LDS, fc2 -> atts.
// No cross-block communication: no atomics, no fences.
// ---------------------------------------------------------------------------
__global__ __launch_bounds__(1024) void pool_mlp(
    const float* __restrict__ emb,
    const float* __restrict__ w1, const float* __restrict__ b1,
    const float* __restrict__ w2, const float* __restrict__ b2,
    float* __restrict__ atts)
{
    const int bg = blockIdx.x;            // b*G + g in [0,256)
    const int g  = bg & 7;
    const int tid  = threadIdx.x;
    const int lane = tid & 63, wave = tid >> 6;   // 16 waves

    __shared__ float pin[CIN];   // pooled means
    __shared__ float h[HID];

    // ---- pool: wave w handles channels 4w..4w+3, fully coalesced ----
    const float4* base = reinterpret_cast<const float4*>(emb) +
                         (size_t)bg * (CIN * (HW / 4));
    #pragma unroll
    for (int c = 0; c < 4; ++c) {
        const int ch = wave * 4 + c;
        const float4* p = base + (size_t)ch * (HW / 4);
        float s = 0.f;
        #pragma unroll
        for (int k = 0; k < 16; ++k) {
            float4 v = p[lane + k * 64];
            s += v.x + v.y + v.z + v.w;
        }
        #pragma unroll
        for (int off = 32; off; off >>= 1) s += __shfl_down(s, off);
        if (lane == 0) pin[ch] = s * (1.0f / HW);
    }
    __syncthreads();

    // ---- fc1: h[o] = relu(b1 + dot(pin, W1[o,:])) , threads 0..511 ----
    if (tid < HID) {
        const float* W1 = w1 + (size_t)g * HID * CIN;
        const float4* wrow = reinterpret_cast<const float4*>(W1 + (size_t)tid * CIN);
        float acc = b1[g * HID + tid];
        #pragma unroll
        for (int i = 0; i < CIN / 4; ++i) {
            float4 w = wrow[i];
            acc += w.x * pin[4 * i] + w.y * pin[4 * i + 1] +
                   w.z * pin[4 * i + 2] + w.w * pin[4 * i + 3];
        }
        h[tid] = fmaxf(acc, 0.f);
    }
    __syncthreads();

    // ---- fc2: 4 threads per output, each does a 128-wide chunk ----
    {
        const int o = tid >> 2, q = tid & 3;
        const float* W2 = w2 + (size_t)g * CO * HID;
        const float4* wrow = reinterpret_cast<const float4*>(W2 + (size_t)o * HID) + q * 32;
        const float* hq = h + q * 128;
        float acc = 0.f;
        #pragma unroll 8
        for (int i = 0; i < 32; ++i) {
            float4 w = wrow[i];
            acc += w.x * hq[4 * i] + w.y * hq[4 * i + 1] +
                   w.z * hq[4 * i + 2] + w.w * hq[4 * i + 3];
        }
        acc += __shfl_down(acc, 2, 4);
        acc += __shfl_down(acc, 1, 4);
        if (q == 0) atts[(size_t)bg * CO + o] = acc + b2[g * CO + o];
    }
}

// ---------------------------------------------------------------------------
// K2: 64 blocks per batch. Each block redundantly computes the (tiny)
// routing for its batch from atts, then scales its 4 channels of x.
// Deterministic: fixed-order FP, identical inputs -> identical matt.
// ---------------------------------------------------------------------------
__global__ __launch_bounds__(256) void route_scale(
    const float* __restrict__ x, const float* __restrict__ atts,
    float* __restrict__ out)
{
    const int bid = blockIdx.x, tid = threadIdx.x;
    const int b = bid >> 6;           // batch
    const int slice = bid & 63;       // 4-channel slice within batch

    __shared__ float xr[G_ * CAPS * OUTC];   // 2048
    __shared__ float beta[G_ * CAPS];
    __shared__ float alpha[G_ * CAPS];
    __shared__ float vv[CAPS * OUTC];        // 256
    __shared__ float nrm[CAPS];
    __shared__ float matt_s[CO];

    for (int i = tid; i < G_ * CAPS * OUTC; i += 256)
        xr[i] = atts[(size_t)b * G_ * CO + i];
    if (tid < G_ * CAPS) beta[tid] = 0.f;
    __syncthreads();

    for (int iter = 0; iter < 3; ++iter) {
        if (tid < G_ * CAPS) {
            const int gg = tid / CAPS;
            float m = fmaxf(fmaxf(beta[gg * CAPS + 0], beta[gg * CAPS + 1]),
                            fmaxf(beta[gg * CAPS + 2], beta[gg * CAPS + 3]));
            float se = 0.f;
            #pragma unroll
            for (int c = 0; c < CAPS; ++c) se += expf(beta[gg * CAPS + c] - m);
            alpha[tid] = expf(beta[tid] - m) / se;
        }
        __syncthreads();
        {
            const int c = tid >> 6;
            float acc = 0.f;
            #pragma unroll
            for (int gg = 0; gg < G_; ++gg)
                acc += alpha[gg * CAPS + c] * xr[(gg * CAPS + c) * OUTC + (tid & 63)];
            vv[tid] = acc;
        }
        __syncthreads();
        if (iter == 2) {
            matt_s[tid] = 1.f / (1.f + expf(-vv[tid]));
        } else {
            float sq = vv[tid] * vv[tid];
            #pragma unroll
            for (int off = 32; off; off >>= 1) sq += __shfl_down(sq, off);
            if ((tid & 63) == 0) nrm[tid >> 6] = sqrtf(sq);
            __syncthreads();
            if (tid < G_ * CAPS) {
                const int gg = tid / CAPS, c = tid % CAPS;
                const float inv = 1.f / fmaxf(nrm[c], 1e-12f);
                float acc = 0.f;
                #pragma unroll
                for (int o = 0; o < OUTC; ++o)
                    acc += vv[c * OUTC + o] * xr[(gg * CAPS + c) * OUTC + o];
                beta[tid] += acc * inv;
            }
            __syncthreads();
        }
    }
    __syncthreads();

    // ---- scale: 4 channels = slice*4 .. slice*4+3 of batch b ----
    const int c0 = slice * 4;
    #pragma unroll
    for (int c = 0; c < 4; ++c) {
        const int ch = b * CO + c0 + c;           // global channel
        const float s = matt_s[c0 + c];
        const float4* xi = reinterpret_cast<const float4*>(x + (size_t)ch * HW);
        float4* oo = reinterpret_cast<float4*>(out + (size_t)ch * HW);
        #pragma unroll
        for (int k = 0; k < 4; ++k) {
            float4 v = xi[tid + k * 256];
            v.x *= s; v.y *= s; v.z *= s; v.w *= s;
            oo[tid + k * 256] = v;
        }
    }
}

extern "C" void kernel_launch(void* const* d_in, const int* in_sizes, int n_in,
                              void* d_out, int out_size, void* d_ws, size_t ws_size,
                              hipStream_t stream) {
    const float* emb = (const float*)d_in[0];
    const float* x   = (const float*)d_in[1];
    const float* w1  = (const float*)d_in[2];
    const float* b1  = (const float*)d_in[3];
    const float* w2  = (const float*)d_in[4];
    const float* b2  = (const float*)d_in[5];
    float* out  = (float*)d_out;
    float* atts = (float*)d_ws;               // B*G*CO = 65536 floats

    pool_mlp<<<B_ * G_, 1024, 0, stream>>>(emb, w1, b1, w2, b2, atts);
    route_scale<<<B_ * 64, 256, 0, stream>>>(x, atts, out);
}

// Round 7
// 134.684 us; speedup vs baseline: 9.4526x; 1.0365x over previous
//
#include <hip/hip_runtime.h>
#include <math.h>

// Problem constants
constexpr int B_   = 32;
constexpr int G_   = 8;
constexpr int CIN  = 64;
constexpr int CAPS = 4;
constexpr int OUTC = 64;
constexpr int HID  = 512;           // CIN * RATIO
constexpr int CO   = CAPS * OUTC;   // 256
constexpr int HW   = 64 * 64;       // 4096

// ---------------------------------------------------------------------------
// K1: pool. 2048 blocks x 256 threads (8 blocks/CU, 32 waves/CU).
// Each wave owns 2 channels; both 16-float4 bursts issue before any reduce.
// ---------------------------------------------------------------------------
__global__ __launch_bounds__(256) void pool_kernel(const float* __restrict__ emb,
                                                   float* __restrict__ pooled) {
    const int bid = blockIdx.x, tid = threadIdx.x;
    const int lane = tid & 63, wave = tid >> 6;
    const int ch0 = bid * 8 + wave * 2;     // 2048 blocks * 8 ch = 16384
    const float4* p0 = reinterpret_cast<const float4*>(emb) + (size_t)ch0 * (HW / 4);
    const float4* p1 = p0 + (HW / 4);
    float s0 = 0.f, s1 = 0.f;
    #pragma unroll
    for (int k = 0; k < 16; ++k) {
        float4 v = p0[lane + k * 64];
        s0 += v.x + v.y + v.z + v.w;
    }
    #pragma unroll
    for (int k = 0; k < 16; ++k) {
        float4 v = p1[lane + k * 64];
        s1 += v.x + v.y + v.z + v.w;
    }
    #pragma unroll
    for (int off = 32; off; off >>= 1) {
        s0 += __shfl_down(s0, off);
        s1 += __shfl_down(s1, off);
    }
    if (lane == 0) {
        pooled[ch0]     = s0 * (1.0f / HW);
        pooled[ch0 + 1] = s1 * (1.0f / HW);
    }
}

// ---------------------------------------------------------------------------
// K2: per (b,g): h = relu(pooled @ w1^T + b1); atts = h @ w2^T + b2
// (verified in R1)
// ---------------------------------------------------------------------------
__global__ __launch_bounds__(256) void fc_kernel(const float* __restrict__ pooled,
                                                 const float* __restrict__ w1,
                                                 const float* __restrict__ b1,
                                                 const float* __restrict__ w2,
                                                 const float* __restrict__ b2,
                                                 float* __restrict__ atts) {
    const int bg = blockIdx.x;
    const int g = bg % G_;
    __shared__ float pin[CIN];
    __shared__ float h[HID];
    const int t = threadIdx.x;
    if (t < CIN) pin[t] = pooled[(size_t)bg * CIN + t];
    __syncthreads();

    const float* W1 = w1 + (size_t)g * HID * CIN;
    for (int o = t; o < HID; o += 256) {
        const float4* wrow = reinterpret_cast<const float4*>(W1 + (size_t)o * CIN);
        float acc = b1[g * HID + o];
        #pragma unroll
        for (int i = 0; i < CIN / 4; ++i) {
            float4 w = wrow[i];
            acc += w.x * pin[4 * i] + w.y * pin[4 * i + 1] +
                   w.z * pin[4 * i + 2] + w.w * pin[4 * i + 3];
        }
        h[o] = fmaxf(acc, 0.f);
    }
    __syncthreads();

    {
        const int o = t;  // 256 threads == CO outputs
        const float* W2 = w2 + (size_t)g * CO * HID;
        const float4* wrow = reinterpret_cast<const float4*>(W2 + (size_t)o * HID);
        float acc = b2[g * CO + o];
        #pragma unroll 8
        for (int i = 0; i < HID / 4; ++i) {
            float4 w = wrow[i];
            acc += w.x * h[4 * i] + w.y * h[4 * i + 1] +
                   w.z * h[4 * i + 2] + w.w * h[4 * i + 3];
        }
        atts[(size_t)bg * CO + o] = acc;
    }
}

// ---------------------------------------------------------------------------
// K3: dynamic routing per batch; writes matt[b][CO] = sigmoid(routed)
// (verified in R1)
// ---------------------------------------------------------------------------
__global__ __launch_bounds__(256) void routing_kernel(const float* __restrict__ atts,
                                                      float* __restrict__ matt) {
    const int b = blockIdx.x;
    __shared__ float xr[G_ * CAPS * OUTC];   // 2048
    __shared__ float beta[G_ * CAPS];
    __shared__ float alpha[G_ * CAPS];
    __shared__ float vv[CAPS * OUTC];        // 256
    __shared__ float nrm[CAPS];
    const int t = threadIdx.x;
    for (int i = t; i < G_ * CAPS * OUTC; i += 256)
        xr[i] = atts[(size_t)b * G_ * CO + i];
    if (t < G_ * CAPS) beta[t] = 0.f;
    __syncthreads();

    for (int iter = 0; iter < 3; ++iter) {
        if (t < G_ * CAPS) {
            const int g = t / CAPS;
            float m = fmaxf(fmaxf(beta[g * CAPS + 0], beta[g * CAPS + 1]),
                            fmaxf(beta[g * CAPS + 2], beta[g * CAPS + 3]));
            float se = 0.f;
            #pragma unroll
            for (int c = 0; c < CAPS; ++c) se += expf(beta[g * CAPS + c] - m);
            alpha[t] = expf(beta[t] - m) / se;
        }
        __syncthreads();
        {
            const int c = t >> 6;
            float acc = 0.f;
            #pragma unroll
            for (int g = 0; g < G_; ++g)
                acc += alpha[g * CAPS + c] * xr[(g * CAPS + c) * OUTC + (t & 63)];
            vv[t] = acc;
        }
        __syncthreads();
        if (iter == 2) {
            matt[(size_t)b * CO + t] = 1.f / (1.f + expf(-vv[t]));
        } else {
            float sq = vv[t] * vv[t];
            #pragma unroll
            for (int off = 32; off; off >>= 1) sq += __shfl_down(sq, off);
            if ((t & 63) == 0) nrm[t >> 6] = sqrtf(sq);
            __syncthreads();
            if (t < G_ * CAPS) {
                const int g = t / CAPS, c = t % CAPS;
                const float inv = 1.f / fmaxf(nrm[c], 1e-12f);
                float acc = 0.f;
                #pragma unroll
                for (int o = 0; o < OUTC; ++o)
                    acc += vv[c * OUTC + o] * xr[(g * CAPS + c) * OUTC + o];
                beta[t] += acc * inv;
            }
            __syncthreads();
        }
    }
}

// ---------------------------------------------------------------------------
// K4: out[ch,:] = matt[ch] * x[ch,:]; 4 channels per block, deep unroll.
// ---------------------------------------------------------------------------
__global__ __launch_bounds__(256) void scale_kernel(const float* __restrict__ x,
                                                    const float* __restrict__ matt,
                                                    float* __restrict__ out) {
    const int bid = blockIdx.x, tid = threadIdx.x;
    const int ch0 = bid * 4;                 // 2048 blocks * 4 ch = 8192
    #pragma unroll
    for (int c = 0; c < 4; ++c) {
        const float s = matt[ch0 + c];
        const float4* xi = reinterpret_cast<const float4*>(x) + (size_t)(ch0 + c) * (HW / 4);
        float4* oo = reinterpret_cast<float4*>(out) + (size_t)(ch0 + c) * (HW / 4);
        #pragma unroll
        for (int k = 0; k < 4; ++k) {
            float4 v = xi[tid + k * 256];
            v.x *= s; v.y *= s; v.z *= s; v.w *= s;
            oo[tid + k * 256] = v;
        }
    }
}

extern "C" void kernel_launch(void* const* d_in, const int* in_sizes, int n_in,
                              void* d_out, int out_size, void* d_ws, size_t ws_size,
                              hipStream_t stream) {
    const float* emb = (const float*)d_in[0];
    const float* x   = (const float*)d_in[1];
    const float* w1  = (const float*)d_in[2];
    const float* b1  = (const float*)d_in[3];
    const float* w2  = (const float*)d_in[4];
    const float* b2  = (const float*)d_in[5];
    float* out = (float*)d_out;

    float* wsf    = (float*)d_ws;
    float* pooled = wsf;                      // 16384
    float* atts   = wsf + 16384;              // 65536
    float* matt   = wsf + 16384 + 65536;      // 8192

    pool_kernel<<<2048, 256, 0, stream>>>(emb, pooled);
    fc_kernel<<<B_ * G_, 256, 0, stream>>>(pooled, w1, b1, w2, b2, atts);
    routing_kernel<<<B_, 256, 0, stream>>>(atts, matt);
    scale_kernel<<<2048, 256, 0, stream>>>(x, matt, out);
}

// Round 9
// 120.682 us; speedup vs baseline: 10.5493x; 1.1160x over previous
//
#include <hip/hip_runtime.h>
#include <math.h>

// Problem constants
constexpr int B_   = 32;
constexpr int G_   = 8;
constexpr int CIN  = 64;
constexpr int CAPS = 4;
constexpr int OUTC = 64;
constexpr int HID  = 512;           // CIN * RATIO
constexpr int CO   = CAPS * OUTC;   // 256
constexpr int HW   = 64 * 64;       // 4096

typedef float __attribute__((ext_vector_type(4))) f32x4;

// ---------------------------------------------------------------------------
// K1: pool. 2048 blocks x 256 threads (8 blocks/CU, 32 waves/CU).
// Non-temporal loads: emb is stream-once, never reused -> bypass cache alloc.
// ---------------------------------------------------------------------------
__global__ __launch_bounds__(256) void pool_kernel(const float* __restrict__ emb,
                                                   float* __restrict__ pooled) {
    const int bid = blockIdx.x, tid = threadIdx.x;
    const int lane = tid & 63, wave = tid >> 6;
    const int ch0 = bid * 8 + wave * 2;     // 2048 blocks * 8 ch = 16384
    const f32x4* p0 = reinterpret_cast<const f32x4*>(emb) + (size_t)ch0 * (HW / 4);
    const f32x4* p1 = p0 + (HW / 4);
    float s0 = 0.f, s1 = 0.f;
    #pragma unroll
    for (int k = 0; k < 16; ++k) {
        f32x4 v = __builtin_nontemporal_load(&p0[lane + k * 64]);
        s0 += v.x + v.y + v.z + v.w;
    }
    #pragma unroll
    for (int k = 0; k < 16; ++k) {
        f32x4 v = __builtin_nontemporal_load(&p1[lane + k * 64]);
        s1 += v.x + v.y + v.z + v.w;
    }
    #pragma unroll
    for (int off = 32; off; off >>= 1) {
        s0 += __shfl_down(s0, off);
        s1 += __shfl_down(s1, off);
    }
    if (lane == 0) {
        pooled[ch0]     = s0 * (1.0f / HW);
        pooled[ch0 + 1] = s1 * (1.0f / HW);
    }
}

// ---------------------------------------------------------------------------
// K2: per (b,g): h = relu(pooled @ w1^T + b1); atts = h @ w2^T + b2
// (weights ARE reused across blocks -> keep normal cached loads)
// ---------------------------------------------------------------------------
__global__ __launch_bounds__(256) void fc_kernel(const float* __restrict__ pooled,
                                                 const float* __restrict__ w1,
                                                 const float* __restrict__ b1,
                                                 const float* __restrict__ w2,
                                                 const float* __restrict__ b2,
                                                 float* __restrict__ atts) {
    const int bg = blockIdx.x;
    const int g = bg % G_;
    __shared__ float pin[CIN];
    __shared__ float h[HID];
    const int t = threadIdx.x;
    if (t < CIN) pin[t] = pooled[(size_t)bg * CIN + t];
    __syncthreads();

    const float* W1 = w1 + (size_t)g * HID * CIN;
    for (int o = t; o < HID; o += 256) {
        const float4* wrow = reinterpret_cast<const float4*>(W1 + (size_t)o * CIN);
        float acc = b1[g * HID + o];
        #pragma unroll
        for (int i = 0; i < CIN / 4; ++i) {
            float4 w = wrow[i];
            acc += w.x * pin[4 * i] + w.y * pin[4 * i + 1] +
                   w.z * pin[4 * i + 2] + w.w * pin[4 * i + 3];
        }
        h[o] = fmaxf(acc, 0.f);
    }
    __syncthreads();

    {
        const int o = t;  // 256 threads == CO outputs
        const float* W2 = w2 + (size_t)g * CO * HID;
        const float4* wrow = reinterpret_cast<const float4*>(W2 + (size_t)o * HID);
        float acc = b2[g * CO + o];
        #pragma unroll 8
        for (int i = 0; i < HID / 4; ++i) {
            float4 w = wrow[i];
            acc += w.x * h[4 * i] + w.y * h[4 * i + 1] +
                   w.z * h[4 * i + 2] + w.w * h[4 * i + 3];
        }
        atts[(size_t)bg * CO + o] = acc;
    }
}

// ---------------------------------------------------------------------------
// K3: dynamic routing per batch; writes matt[b][CO] = sigmoid(routed)
// ---------------------------------------------------------------------------
__global__ __launch_bounds__(256) void routing_kernel(const float* __restrict__ atts,
                                                      float* __restrict__ matt) {
    const int b = blockIdx.x;
    __shared__ float xr[G_ * CAPS * OUTC];   // 2048
    __shared__ float beta[G_ * CAPS];
    __shared__ float alpha[G_ * CAPS];
    __shared__ float vv[CAPS * OUTC];        // 256
    __shared__ float nrm[CAPS];
    const int t = threadIdx.x;
    for (int i = t; i < G_ * CAPS * OUTC; i += 256)
        xr[i] = atts[(size_t)b * G_ * CO + i];
    if (t < G_ * CAPS) beta[t] = 0.f;
    __syncthreads();

    for (int iter = 0; iter < 3; ++iter) {
        if (t < G_ * CAPS) {
            const int g = t / CAPS;
            float m = fmaxf(fmaxf(beta[g * CAPS + 0], beta[g * CAPS + 1]),
                            fmaxf(beta[g * CAPS + 2], beta[g * CAPS + 3]));
            float se = 0.f;
            #pragma unroll
            for (int c = 0; c < CAPS; ++c) se += expf(beta[g * CAPS + c] - m);
            alpha[t] = expf(beta[t] - m) / se;
        }
        __syncthreads();
        {
            const int c = t >> 6;
            float acc = 0.f;
            #pragma unroll
            for (int g = 0; g < G_; ++g)
                acc += alpha[g * CAPS + c] * xr[(g * CAPS + c) * OUTC + (t & 63)];
            vv[t] = acc;
        }
        __syncthreads();
        if (iter == 2) {
            matt[(size_t)b * CO + t] = 1.f / (1.f + expf(-vv[t]));
        } else {
            float sq = vv[t] * vv[t];
            #pragma unroll
            for (int off = 32; off; off >>= 1) sq += __shfl_down(sq, off);
            if ((t & 63) == 0) nrm[t >> 6] = sqrtf(sq);
            __syncthreads();
            if (t < G_ * CAPS) {
                const int g = t / CAPS, c = t % CAPS;
                const float inv = 1.f / fmaxf(nrm[c], 1e-12f);
                float acc = 0.f;
                #pragma unroll
                for (int o = 0; o < OUTC; ++o)
                    acc += vv[c * OUTC + o] * xr[(g * CAPS + c) * OUTC + o];
                beta[t] += acc * inv;
            }
            __syncthreads();
        }
    }
}

// ---------------------------------------------------------------------------
// K4: out[ch,:] = matt[ch] * x[ch,:]; 4 channels per block.
// Non-temporal: x read-once, out write-once -> bypass cache allocation.
// ---------------------------------------------------------------------------
__global__ __launch_bounds__(256) void scale_kernel(const float* __restrict__ x,
                                                    const float* __restrict__ matt,
                                                    float* __restrict__ out) {
    const int bid = blockIdx.x, tid = threadIdx.x;
    const int ch0 = bid * 4;                 // 2048 blocks * 4 ch = 8192
    #pragma unroll
    for (int c = 0; c < 4; ++c) {
        const float s = matt[ch0 + c];
        const f32x4* xi = reinterpret_cast<const f32x4*>(x) + (size_t)(ch0 + c) * (HW / 4);
        f32x4* oo = reinterpret_cast<f32x4*>(out) + (size_t)(ch0 + c) * (HW / 4);
        #pragma unroll
        for (int k = 0; k < 4; ++k) {
            f32x4 v = __builtin_nontemporal_load(&xi[tid + k * 256]);
            v.x *= s; v.y *= s; v.z *= s; v.w *= s;
            __builtin_nontemporal_store(v, &oo[tid + k * 256]);
        }
    }
}

extern "C" void kernel_launch(void* const* d_in, const int* in_sizes, int n_in,
                              void* d_out, int out_size, void* d_ws, size_t ws_size,
                              hipStream_t stream) {
    const float* emb = (const float*)d_in[0];
    const float* x   = (const float*)d_in[1];
    const float* w1  = (const float*)d_in[2];
    const float* b1  = (const float*)d_in[3];
    const float* w2  = (const float*)d_in[4];
    const float* b2  = (const float*)d_in[5];
    float* out = (float*)d_out;

    float* wsf    = (float*)d_ws;
    float* pooled = wsf;                      // 16384
    float* atts   = wsf + 16384;              // 65536
    float* matt   = wsf + 16384 + 65536;      // 8192

    pool_kernel<<<2048, 256, 0, stream>>>(emb, pooled);
    fc_kernel<<<B_ * G_, 256, 0, stream>>>(pooled, w1, b1, w2, b2, atts);
    routing_kernel<<<B_, 256, 0, stream>>>(atts, matt);
    scale_kernel<<<2048, 256, 0, stream>>>(x, matt, out);
}